// Round 13
// baseline (124.395 us; speedup 1.0000x reference)
//
#include <hip/hip_runtime.h>
#include <math.h>

#define EDIM 128
#define NHEAD 16
#define HDIM 8
#define SEQ 2048
#define BATCH 4
#define NROW (BATCH*SEQ)            // 8192
// -scale*log2(e): folded into Q at projection time so sigmoid = rcp(1+exp2(dot))
#define QNEG (-0.35355339059327373f * 1.4426950408889634f)

#if __has_builtin(__builtin_amdgcn_exp2f)
#define EXP2F(x) __builtin_amdgcn_exp2f(x)
#else
#define EXP2F(x) exp2f(x)
#endif
#define RCPF(x) __builtin_amdgcn_rcpf(x)

typedef __attribute__((ext_vector_type(8))) short short8v;
typedef __attribute__((ext_vector_type(4))) short short4v;
typedef __attribute__((ext_vector_type(4))) float float4v;
typedef __attribute__((ext_vector_type(16))) float float16v;

union U16x8 { uint4 u; short8v s; };
union U16x4 { uint2 u; short4v s; };

#define MFMA32(a,b,c) __builtin_amdgcn_mfma_f32_32x32x16_bf16(a,b,c,0,0,0)

// v_permlane32_swap_b32: vdst.hi <-> vsrc.lo.
// After: x = [x.lo, y.lo_old], y = [x.hi_old, y.hi]  (lane i+32 of x gets
// lane i of y, lane i of y gets lane i+32 of x -- same q since q = l&31).
__device__ __forceinline__ void lane32swap(unsigned &x, unsigned &y) {
#if __has_builtin(__builtin_amdgcn_permlane32_swap)
  typedef __attribute__((ext_vector_type(2))) unsigned uint2v;
  uint2v r = __builtin_amdgcn_permlane32_swap(x, y, false, false);
  x = r[0]; y = r[1];
#else
  asm volatile("v_permlane32_swap_b32 %0, %1" : "+v"(x), "+v"(y));
#endif
}

// pack two floats to bf16x2, round-to-nearest-even-ish (values finite)
__device__ __forceinline__ unsigned pk_bf16(float a, float b) {
  unsigned ua = __float_as_uint(a), ub = __float_as_uint(b);
  unsigned lo = (ua + 0x7fffu + ((ua >> 16) & 1u)) >> 16;
  unsigned hi = (ub + 0x7fffu + ((ub >> 16) & 1u)) & 0xffff0000u;
  return lo | hi;
}

__device__ __forceinline__ float16v zero16() {
  float16v z;
  #pragma unroll
  for (int i = 0; i < 16; ++i) z[i] = 0.f;
  return z;
}

// A-frags from swizzled LDS: A lane l: A[m=l&15][k=(l>>4)*8+j]
__device__ __forceinline__
void afrags(const unsigned short* xs, int lq, int qd, short8v a[4])
{
  #pragma unroll
  for (int kk = 0; kk < 4; ++kk) {
    const unsigned addr =
        (unsigned)(lq * 256 + kk * 64 + qd * 16) ^ (unsigned)((lq & 7) << 4);
    a[kk] = *(const short8v*)((const char*)xs + addr);
  }
}

// ---------------------------------------------------------------------------
// 32-row x 128-col MFMA projection block, W staged per-block into LDS.
// (unchanged from R12 — byte-identical outputs)
// ---------------------------------------------------------------------------
template<int MODE>
__device__ __forceinline__
void proj32(const float* __restrict__ X, const float* __restrict__ W,
            const float* __restrict__ bias, void* __restrict__ out,
            int row0, int tid,
            unsigned short* wlds, unsigned short* xs, unsigned short* bnc)
{
  // ---- stage W: 2 threads per row, 64 cols (16 float4) each, coalesced ----
  {
    const int n = tid >> 1, h = (tid & 1) * 64;
    const float4* src = (const float4*)(W + (size_t)n * EDIM + h);
    const unsigned xr = (unsigned)((n & 7) << 4);
    #pragma unroll
    for (int j = 0; j < 8; ++j) {
      const float4 f0 = src[2 * j], f1 = src[2 * j + 1];
      const uint4 v = make_uint4(pk_bf16(f0.x, f0.y), pk_bf16(f0.z, f0.w),
                                 pk_bf16(f1.x, f1.y), pk_bf16(f1.z, f1.w));
      *(uint4*)((char*)wlds + ((unsigned)(n * 256 + h * 2 + j * 16) ^ xr)) = v;
    }
  }
  // ---- stage X: 8 threads per row (32 rows), 16 cols each ----
  {
    const int r = tid >> 3, c = tid & 7;
    const float4* src = (const float4*)(X + (size_t)(row0 + r) * EDIM + c * 16);
    const unsigned xr = (unsigned)((r & 7) << 4);
    const float4 f0 = src[0], f1 = src[1], f2 = src[2], f3 = src[3];
    const uint4 v0 = make_uint4(pk_bf16(f0.x, f0.y), pk_bf16(f0.z, f0.w),
                                pk_bf16(f1.x, f1.y), pk_bf16(f1.z, f1.w));
    const uint4 v1 = make_uint4(pk_bf16(f2.x, f2.y), pk_bf16(f2.z, f2.w),
                                pk_bf16(f3.x, f3.y), pk_bf16(f3.z, f3.w));
    *(uint4*)((char*)xs + ((unsigned)(r * 256 + c * 32) ^ xr)) = v0;
    *(uint4*)((char*)xs + ((unsigned)(r * 256 + c * 32 + 16) ^ xr)) = v1;
  }
  __syncthreads();

  const int lane = tid & 63, wv = tid >> 6;
  const int lq = lane & 15, qd = lane >> 4;
  const int n0 = wv * 32;

  // ---- B-frags once per wave (two 16-col tiles) ----
  short8v b0[4], b1[4];
  #pragma unroll
  for (int kk = 0; kk < 4; ++kk) {
    const unsigned ad = (unsigned)((n0 + lq) * 256 + kk * 64 + qd * 16)
                      ^ (unsigned)((lq & 7) << 4);
    b0[kk] = *(const short8v*)((const char*)wlds + ad);
    b1[kk] = *(const short8v*)((const char*)wlds + ad + 4096);  // +16 rows
  }

  const int nA = n0 + lq, nB = nA + 16;
  const float bzA = bias[nA], bzB = bias[nB];
  const int b_ = row0 >> 11;

  #pragma unroll
  for (int rt = 0; rt < 2; ++rt) {
    const int rowt = row0 + rt * 16;
    short8v a[4];
    afrags(xs + rt * 2048, lq, qd, a);

    float4v D0 = {0.f, 0.f, 0.f, 0.f}, D1 = {0.f, 0.f, 0.f, 0.f};
    #pragma unroll
    for (int kk = 0; kk < 4; ++kk) {
      D0 = __builtin_amdgcn_mfma_f32_16x16x32_bf16(a[kk], b0[kk], D0, 0, 0, 0);
      D1 = __builtin_amdgcn_mfma_f32_16x16x32_bf16(a[kk], b1[kk], D1, 0, 0, 0);
    }

    if (MODE == 3) {
      float* of = (float*)out + (size_t)(rowt + qd * 4) * EDIM + nA;
      #pragma unroll
      for (int r = 0; r < 4; ++r) {
        of[r * EDIM]      = D0[r] + bzA;
        of[r * EDIM + 16] = D1[r] + bzB;
      }
      continue;
    }

    const int srel = rowt & (SEQ - 1);

    if (MODE == 2) {
      // Vt[bh][tg][d][si]: row-tile = one 16-s tile; si = qd*4 + r.
      const int tg = srel >> 4;
      unsigned short* oU = (unsigned short*)out;
      {
        const int bh = b_ * NHEAD + (nA >> 3), dv = nA & 7;
        uint2 p;
        p.x = pk_bf16(D0[0] + bzA, D0[1] + bzA);
        p.y = pk_bf16(D0[2] + bzA, D0[3] + bzA);
        *(uint2*)(oU + (size_t)bh * (SEQ * HDIM) + tg * 128 + dv * 16 + qd * 4) = p;
      }
      {
        const int bh = b_ * NHEAD + (nB >> 3), dv = nB & 7;
        uint2 p;
        p.x = pk_bf16(D1[0] + bzB, D1[1] + bzB);
        p.y = pk_bf16(D1[2] + bzB, D1[3] + bzB);
        *(uint2*)(oU + (size_t)bh * (SEQ * HDIM) + tg * 128 + dv * 16 + qd * 4) = p;
      }
      continue;
    }

    // MODE 0/1: bounce both 16x16 tiles through padded LDS ([16][20] u16),
    // then contiguous 256B uint4 stores (one [bh][s][8] row per lane).
    #pragma unroll
    for (int r = 0; r < 4; ++r) {
      float vA = D0[r] + bzA, vB = D1[r] + bzB;
      if (MODE == 0) { vA *= QNEG; vB *= QNEG; }
      const int m = qd * 4 + r;
      bnc[m * 20 + lq]       = (unsigned short)pk_bf16(vA, 0.f);
      bnc[320 + m * 20 + lq] = (unsigned short)pk_bf16(vB, 0.f);
    }
    __syncthreads();                              // LDS write->read order

    const int mm   = lane & 15;
    const int half = (lane >> 4) & 1;
    const int tile = lane >> 5;
    const unsigned short* sp = bnc + tile * 320 + mm * 20 + half * 8;
    const uint2 w0 = *(const uint2*)sp;
    const uint2 w1 = *(const uint2*)(sp + 4);
    const int bh = b_ * NHEAD + wv * 4 + tile * 2 + half;
    unsigned short* dp = (unsigned short*)out + ((size_t)bh * SEQ + srel + mm) * 8;
    *(uint4*)dp = make_uint4(w0.x, w0.y, w1.x, w1.y);
    __syncthreads();                              // bnc reuse guard (next rt)
  }
}

__global__ __launch_bounds__(256)
void qkv_kernel(const float* __restrict__ X,
                const float* __restrict__ Wq, const float* __restrict__ Wk,
                const float* __restrict__ Wv,
                const float* __restrict__ bq, const float* __restrict__ bk,
                const float* __restrict__ bv,
                unsigned* __restrict__ qb, unsigned* __restrict__ kb,
                unsigned* __restrict__ vb)
{
  __shared__ __align__(16) unsigned short wlds[16384];   // 32 KB
  __shared__ __align__(16) unsigned short xs[4096];      // 8 KB
  __shared__ __align__(16) unsigned short bnc[4 * 640];  // 5 KB
  const int tid = threadIdx.x;
  const int row0 = blockIdx.x * 32;
  unsigned short* myb = bnc + (tid >> 6) * 640;
  const int m = blockIdx.y;
  if (m == 0)      proj32<0>(X, Wq, bq, (void*)qb, row0, tid, wlds, xs, myb);
  else if (m == 1) proj32<1>(X, Wk, bk, (void*)kb, row0, tid, wlds, xs, myb);
  else             proj32<2>(X, Wv, bv, (void*)vb, row0, tid, wlds, xs, myb);
}

__global__ __launch_bounds__(256)
void oproj_kernel(const float* __restrict__ A, const float* __restrict__ Wo,
                  const float* __restrict__ bo, float* __restrict__ out)
{
  __shared__ __align__(16) unsigned short wlds[16384];   // 32 KB
  __shared__ __align__(16) unsigned short xs[4096];      // 8 KB
  proj32<3>(A, Wo, bo, (void*)out, blockIdx.x * 32, threadIdx.x, wlds, xs, nullptr);
}

// ---------------------------------------------------------------------------
// 32q x 32k macro-step (amortizes per-step VALU/loads 4x vs 16x16 steps).
// QK^T: S^T = mfma_32x32x16_bf16(A=K-rows, B=Q) -> C[key][q]:
//   col q = l&31, row key = (reg&3)+8*(reg>>2)+4*(l>>5)   [guide m74/m101]
//   (K dims 8..15 of A are garbage but multiply B's zeroed half -> 0.)
// Sigmoid per element; pack pairs to bf16. A-operand of PV needs lane l to
// hold P[q=l&31][key=(l>>5)*8+j]; the C layout has keys {0-3,8-11,16-19,
// 24-27} in half0 and {4-7,...} in half1. 4 permlane32_swaps fix it:
//   {a0,a2} = swap(u0,u2): a0=[keys(0,1)h0|(8,9)h1], a2=[(4,5)h0|(12,13)h1]
// PV: out[q][d] += P x V, two mfma_32x32x16 (keys 0-15, 16-31). V B-frag
// col n=8 forced to 1.0 -> acc col 8 = denominator (cols 9-31 junk).
// ---------------------------------------------------------------------------
template<bool DIAG>
__device__ __forceinline__
float16v step32(const uint4* __restrict__ Kg,
                const unsigned short* __restrict__ Vtbh,
                int t, U16x8 qf, float16v acc,
                int lane, unsigned voff, bool is8)
{
  U16x8 kf; kf.u = Kg[32 * t + (lane & 31)];
  const unsigned short* vt = Vtbh + 256 * t;
  U16x8 v1, v2;
  {
    const uint4 a = *(const uint4*)(vt + voff);
    const uint4 b = *(const uint4*)(vt + 128 + voff);
    const uint4 ones = make_uint4(0x3F803F80u, 0x3F803F80u,
                                  0x3F803F80u, 0x3F803F80u);
    v1.u = is8 ? ones : a;
    v2.u = is8 ? ones : b;
  }

  float16v st = MFMA32(kf.s, qf.s, zero16());

  unsigned u[8];
  #pragma unroll
  for (int i = 0; i < 8; ++i) {
    float s0 = RCPF(1.f + EXP2F(st[2 * i]));      // Q carries -scale*log2e
    float s1 = RCPF(1.f + EXP2F(st[2 * i + 1]));
    if (DIAG) {                                   // exact: sigma(-1e9)==0
      const int rb = ((2 * i) & 3) + 8 * (i >> 1) + ((lane >> 5) << 2);
      const int q_ = lane & 31;
      s0 = (rb     <= q_) ? s0 : 0.f;
      s1 = (rb + 1 <= q_) ? s1 : 0.f;
    }
    const unsigned b0 = __float_as_uint(s0) + 0x8000u;  // round-half-up bf16
    const unsigned b1 = __float_as_uint(s1) + 0x8000u;
    u[i] = __builtin_amdgcn_perm(b1, b0, 0x07060302u);
  }

  lane32swap(u[0], u[2]);   // -> a0, a2
  lane32swap(u[1], u[3]);   // -> a1, a3
  lane32swap(u[4], u[6]);   // -> b0, b2
  lane32swap(u[5], u[7]);   // -> b1, b3

  U16x8 pa, pb;
  pa.u = make_uint4(u[0], u[1], u[2], u[3]);
  pb.u = make_uint4(u[4], u[5], u[6], u[7]);
  acc = MFMA32(pa.s, v1.s, acc);                  // keys 0-15
  acc = MFMA32(pb.s, v2.s, acc);                  // keys 16-31
  return acc;
}

// run k-tiles [a,b) of tile T; b == T+1 means this wave owns T's diag step
__device__ __forceinline__
void seg32(const uint4* __restrict__ Kg, const unsigned short* __restrict__ Vtbh,
           U16x8 qf, int T, int a, int b, float16v &acc,
           int lane, unsigned voff, bool is8)
{
  if (a >= b) return;
  const bool hasDiag = (b == T + 1);
  const int e = hasDiag ? b - 1 : b;
  for (int t = a; t < e; ++t)
    acc = step32<false>(Kg, Vtbh, t, qf, acc, lane, voff, is8);
  if (hasDiag)
    acc = step32<true>(Kg, Vtbh, T, qf, acc, lane, voff, is8);
}

// epilogue: den = acc col 8 (same half, lane (l&32)|8); store d = l&31 < 8
__device__ __forceinline__
void epilogue32(float16v acc, int T, int bh, int lane, float* __restrict__ out)
{
  const int b_ = bh >> 4, h = bh & 15;
  const int n = lane & 31;
  const int pidx = ((lane & 32) | 8) << 2;
  const int rowb = 32 * T + ((lane >> 5) << 2);
  #pragma unroll
  for (int reg = 0; reg < 16; ++reg) {
    const float den = __int_as_float(
        __builtin_amdgcn_ds_bpermute(pidx, __float_as_int(acc[reg])));
    const float val = acc[reg] * RCPF(den);       // den > 0
    const int row = rowb + (reg & 3) + 8 * (reg >> 2);
    if (n < 8)
      out[(size_t)(b_ * SEQ + row) * EDIM + h * HDIM + n] = val;
  }
}

// ---------------------------------------------------------------------------
// Causal sigmoid-attention v14: 32x32 macro-steps. Fold-pair (L=g, H=63-g in
// 32-row tiles) = 65 macro-steps, flattened-chunk split over 2 waves:
// w0 = steps [0,32) (all of L incl diag + head of H), w1 = [32,65) (tail of
// H incl diag). Grid 2048 blocks = exactly 8/CU. blockIdx low 6 bits = bh.
// ---------------------------------------------------------------------------
__global__ __launch_bounds__(128, 4)
void attn_kernel(const unsigned* __restrict__ Qb, const unsigned* __restrict__ Kb,
                 const unsigned* __restrict__ Vb, float* __restrict__ out)
{
  __shared__ float cmb[2][64][16];                // 8 KB

  const int bh   = blockIdx.x & 63;
  const int g    = blockIdx.x >> 6;               // 0..31
  const int w    = threadIdx.x >> 6;
  const int lane = threadIdx.x & 63;
  const int L = g, H = 63 - g;

  const uint4* Kg = (const uint4*)Kb + (size_t)bh * 2048;
  const uint4* Qg = (const uint4*)Qb + (size_t)bh * 2048;
  const unsigned short* Vtbh = (const unsigned short*)Vb + (size_t)bh * SEQ * HDIM;

  const unsigned voff = (unsigned)((lane & 7) * 16 + ((lane >> 5) << 3));
  const bool is8 = (lane & 31) == 8;

  // Q B-frags: lanes<32 hold Q-row (dims 0-7) for q = lane; half1 zero
  U16x8 qfl, qfh;
  {
    const uint4 zz = make_uint4(0u, 0u, 0u, 0u);
    qfl.u = (lane < 32) ? Qg[32 * L + lane] : zz;
    qfh.u = (lane < 32) ? Qg[32 * H + lane] : zz;
  }

  float16v accL = zero16();
  float16v accH = zero16();

  // flattened 65-step chunk: w0 [0,32), w1 [32,65)
  const int st_ = w ? 32 : 0;
  const int en_ = w ? 65 : 32;
  const int Lp1 = L + 1;
  const int aL = (st_ < Lp1) ? st_ : Lp1;
  const int bL = (en_ < Lp1) ? en_ : Lp1;
  int aH = st_ - Lp1; if (aH < 0) aH = 0;
  int bH = en_ - Lp1; if (bH > H + 1) bH = H + 1;

  seg32(Kg, Vtbh, qfl, L, aL, bL, accL, lane, voff, is8);
  seg32(Kg, Vtbh, qfh, H, aH, bH, accH, lane, voff, is8);

  if (w == 1) {
    #pragma unroll
    for (int i = 0; i < 4; ++i) {
      *(float4*)&cmb[0][lane][4 * i] =
          make_float4(accL[4*i], accL[4*i+1], accL[4*i+2], accL[4*i+3]);
      *(float4*)&cmb[1][lane][4 * i] =
          make_float4(accH[4*i], accH[4*i+1], accH[4*i+2], accH[4*i+3]);
    }
  }
  __syncthreads();

  if (w == 0) {
    #pragma unroll
    for (int i = 0; i < 16; ++i) {
      accL[i] += cmb[0][lane][i];
      accH[i] += cmb[1][lane][i];
    }
    epilogue32(accL, L, bh, lane, out);
    epilogue32(accH, H, bh, lane, out);
  }
}

// ---------------------------------------------------------------------------
extern "C" void kernel_launch(void* const* d_in, const int* in_sizes, int n_in,
                              void* d_out, int out_size, void* d_ws, size_t ws_size,
                              hipStream_t stream)
{
  const float* x  = (const float*)d_in[0];
  const float* Wq = (const float*)d_in[1];
  const float* bq = (const float*)d_in[2];
  const float* Wk = (const float*)d_in[3];
  const float* bk = (const float*)d_in[4];
  const float* Wv = (const float*)d_in[5];
  const float* bv = (const float*)d_in[6];
  const float* Wo = (const float*)d_in[7];
  const float* bo = (const float*)d_in[8];

  float* ws = (float*)d_ws;
  // layout: (64K floats reserved) | attn 1048576 f | Qb, Kb, Vt 524288 dw each
  float*    attn = ws + 65536;
  unsigned* Qb   = (unsigned*)(ws + 65536 + 1048576);
  unsigned* Kb   = Qb + (size_t)524288;
  unsigned* Vb   = Kb + (size_t)524288;

  qkv_kernel<<<dim3(NROW / 32, 3), 256, 0, stream>>>(x, Wq, Wk, Wv, bq, bk, bv,
                                                     Qb, Kb, Vb);
  attn_kernel<<<dim3(2048), 128, 0, stream>>>(Qb, Kb, Vb, attn);
  oproj_kernel<<<dim3(NROW / 32), 256, 0, stream>>>(attn, Wo, bo, (float*)d_out);
}

// Round 14
// 123.723 us; speedup vs baseline: 1.0054x; 1.0054x over previous
//
#include <hip/hip_runtime.h>
#include <math.h>

#define EDIM 128
#define NHEAD 16
#define HDIM 8
#define SEQ 2048
#define BATCH 4
#define NROW (BATCH*SEQ)            // 8192
// -scale*log2(e): folded into Q at projection time so sigmoid = rcp(1+exp2(dot))
#define QNEG (-0.35355339059327373f * 1.4426950408889634f)

#if __has_builtin(__builtin_amdgcn_exp2f)
#define EXP2F(x) __builtin_amdgcn_exp2f(x)
#else
#define EXP2F(x) exp2f(x)
#endif
#define RCPF(x) __builtin_amdgcn_rcpf(x)

typedef __attribute__((ext_vector_type(8))) short short8v;
typedef __attribute__((ext_vector_type(4))) short short4v;
typedef __attribute__((ext_vector_type(4))) float float4v;
typedef __attribute__((ext_vector_type(16))) float float16v;

union U16x8 { uint4 u; short8v s; };
union U16x4 { uint2 u; short4v s; };

#define MFMA32(a,b,c) __builtin_amdgcn_mfma_f32_32x32x16_bf16(a,b,c,0,0,0)

// v_permlane32_swap_b32: vdst.hi <-> vsrc.lo.
__device__ __forceinline__ void lane32swap(unsigned &x, unsigned &y) {
#if __has_builtin(__builtin_amdgcn_permlane32_swap)
  typedef __attribute__((ext_vector_type(2))) unsigned uint2v;
  uint2v r = __builtin_amdgcn_permlane32_swap(x, y, false, false);
  x = r[0]; y = r[1];
#else
  asm volatile("v_permlane32_swap_b32 %0, %1" : "+v"(x), "+v"(y));
#endif
}

// pack two floats to bf16x2, round-to-nearest-even-ish (values finite)
__device__ __forceinline__ unsigned pk_bf16(float a, float b) {
  unsigned ua = __float_as_uint(a), ub = __float_as_uint(b);
  unsigned lo = (ua + 0x7fffu + ((ua >> 16) & 1u)) >> 16;
  unsigned hi = (ub + 0x7fffu + ((ub >> 16) & 1u)) & 0xffff0000u;
  return lo | hi;
}

__device__ __forceinline__ float16v zero16() {
  float16v z;
  #pragma unroll
  for (int i = 0; i < 16; ++i) z[i] = 0.f;
  return z;
}

// A-frags from swizzled LDS: A lane l: A[m=l&15][k=(l>>4)*8+j]
__device__ __forceinline__
void afrags(const unsigned short* xs, int lq, int qd, short8v a[4])
{
  #pragma unroll
  for (int kk = 0; kk < 4; ++kk) {
    const unsigned addr =
        (unsigned)(lq * 256 + kk * 64 + qd * 16) ^ (unsigned)((lq & 7) << 4);
    a[kk] = *(const short8v*)((const char*)xs + addr);
  }
}

// ---------------------------------------------------------------------------
// 32-row x 128-col MFMA projection block, W staged per-block into LDS.
// (unchanged from R12 — byte-identical outputs)
// ---------------------------------------------------------------------------
template<int MODE>
__device__ __forceinline__
void proj32(const float* __restrict__ X, const float* __restrict__ W,
            const float* __restrict__ bias, void* __restrict__ out,
            int row0, int tid,
            unsigned short* wlds, unsigned short* xs, unsigned short* bnc)
{
  // ---- stage W: 2 threads per row, 64 cols (16 float4) each, coalesced ----
  {
    const int n = tid >> 1, h = (tid & 1) * 64;
    const float4* src = (const float4*)(W + (size_t)n * EDIM + h);
    const unsigned xr = (unsigned)((n & 7) << 4);
    #pragma unroll
    for (int j = 0; j < 8; ++j) {
      const float4 f0 = src[2 * j], f1 = src[2 * j + 1];
      const uint4 v = make_uint4(pk_bf16(f0.x, f0.y), pk_bf16(f0.z, f0.w),
                                 pk_bf16(f1.x, f1.y), pk_bf16(f1.z, f1.w));
      *(uint4*)((char*)wlds + ((unsigned)(n * 256 + h * 2 + j * 16) ^ xr)) = v;
    }
  }
  // ---- stage X: 8 threads per row (32 rows), 16 cols each ----
  {
    const int r = tid >> 3, c = tid & 7;
    const float4* src = (const float4*)(X + (size_t)(row0 + r) * EDIM + c * 16);
    const unsigned xr = (unsigned)((r & 7) << 4);
    const float4 f0 = src[0], f1 = src[1], f2 = src[2], f3 = src[3];
    const uint4 v0 = make_uint4(pk_bf16(f0.x, f0.y), pk_bf16(f0.z, f0.w),
                                pk_bf16(f1.x, f1.y), pk_bf16(f1.z, f1.w));
    const uint4 v1 = make_uint4(pk_bf16(f2.x, f2.y), pk_bf16(f2.z, f2.w),
                                pk_bf16(f3.x, f3.y), pk_bf16(f3.z, f3.w));
    *(uint4*)((char*)xs + ((unsigned)(r * 256 + c * 32) ^ xr)) = v0;
    *(uint4*)((char*)xs + ((unsigned)(r * 256 + c * 32 + 16) ^ xr)) = v1;
  }
  __syncthreads();

  const int lane = tid & 63, wv = tid >> 6;
  const int lq = lane & 15, qd = lane >> 4;
  const int n0 = wv * 32;

  // ---- B-frags once per wave (two 16-col tiles) ----
  short8v b0[4], b1[4];
  #pragma unroll
  for (int kk = 0; kk < 4; ++kk) {
    const unsigned ad = (unsigned)((n0 + lq) * 256 + kk * 64 + qd * 16)
                      ^ (unsigned)((lq & 7) << 4);
    b0[kk] = *(const short8v*)((const char*)wlds + ad);
    b1[kk] = *(const short8v*)((const char*)wlds + ad + 4096);  // +16 rows
  }

  const int nA = n0 + lq, nB = nA + 16;
  const float bzA = bias[nA], bzB = bias[nB];
  const int b_ = row0 >> 11;

  #pragma unroll
  for (int rt = 0; rt < 2; ++rt) {
    const int rowt = row0 + rt * 16;
    short8v a[4];
    afrags(xs + rt * 2048, lq, qd, a);

    float4v D0 = {0.f, 0.f, 0.f, 0.f}, D1 = {0.f, 0.f, 0.f, 0.f};
    #pragma unroll
    for (int kk = 0; kk < 4; ++kk) {
      D0 = __builtin_amdgcn_mfma_f32_16x16x32_bf16(a[kk], b0[kk], D0, 0, 0, 0);
      D1 = __builtin_amdgcn_mfma_f32_16x16x32_bf16(a[kk], b1[kk], D1, 0, 0, 0);
    }

    if (MODE == 3) {
      float* of = (float*)out + (size_t)(rowt + qd * 4) * EDIM + nA;
      #pragma unroll
      for (int r = 0; r < 4; ++r) {
        of[r * EDIM]      = D0[r] + bzA;
        of[r * EDIM + 16] = D1[r] + bzB;
      }
      continue;
    }

    const int srel = rowt & (SEQ - 1);

    if (MODE == 2) {
      // Vt[bh][tg][d][si]: row-tile = one 16-s tile; si = qd*4 + r.
      const int tg = srel >> 4;
      unsigned short* oU = (unsigned short*)out;
      {
        const int bh = b_ * NHEAD + (nA >> 3), dv = nA & 7;
        uint2 p;
        p.x = pk_bf16(D0[0] + bzA, D0[1] + bzA);
        p.y = pk_bf16(D0[2] + bzA, D0[3] + bzA);
        *(uint2*)(oU + (size_t)bh * (SEQ * HDIM) + tg * 128 + dv * 16 + qd * 4) = p;
      }
      {
        const int bh = b_ * NHEAD + (nB >> 3), dv = nB & 7;
        uint2 p;
        p.x = pk_bf16(D1[0] + bzB, D1[1] + bzB);
        p.y = pk_bf16(D1[2] + bzB, D1[3] + bzB);
        *(uint2*)(oU + (size_t)bh * (SEQ * HDIM) + tg * 128 + dv * 16 + qd * 4) = p;
      }
      continue;
    }

    // MODE 0/1: bounce both 16x16 tiles through padded LDS ([16][20] u16),
    // then contiguous 256B uint4 stores (one [bh][s][8] row per lane).
    #pragma unroll
    for (int r = 0; r < 4; ++r) {
      float vA = D0[r] + bzA, vB = D1[r] + bzB;
      if (MODE == 0) { vA *= QNEG; vB *= QNEG; }
      const int m = qd * 4 + r;
      bnc[m * 20 + lq]       = (unsigned short)pk_bf16(vA, 0.f);
      bnc[320 + m * 20 + lq] = (unsigned short)pk_bf16(vB, 0.f);
    }
    __syncthreads();                              // LDS write->read order

    const int mm   = lane & 15;
    const int half = (lane >> 4) & 1;
    const int tile = lane >> 5;
    const unsigned short* sp = bnc + tile * 320 + mm * 20 + half * 8;
    const uint2 w0 = *(const uint2*)sp;
    const uint2 w1 = *(const uint2*)(sp + 4);
    const int bh = b_ * NHEAD + wv * 4 + tile * 2 + half;
    unsigned short* dp = (unsigned short*)out + ((size_t)bh * SEQ + srel + mm) * 8;
    *(uint4*)dp = make_uint4(w0.x, w0.y, w1.x, w1.y);
    __syncthreads();                              // bnc reuse guard (next rt)
  }
}

__global__ __launch_bounds__(256)
void qkv_kernel(const float* __restrict__ X,
                const float* __restrict__ Wq, const float* __restrict__ Wk,
                const float* __restrict__ Wv,
                const float* __restrict__ bq, const float* __restrict__ bk,
                const float* __restrict__ bv,
                unsigned* __restrict__ qb, unsigned* __restrict__ kb,
                unsigned* __restrict__ vb)
{
  __shared__ __align__(16) unsigned short wlds[16384];   // 32 KB
  __shared__ __align__(16) unsigned short xs[4096];      // 8 KB
  __shared__ __align__(16) unsigned short bnc[4 * 640];  // 5 KB
  const int tid = threadIdx.x;
  const int row0 = blockIdx.x * 32;
  unsigned short* myb = bnc + (tid >> 6) * 640;
  const int m = blockIdx.y;
  if (m == 0)      proj32<0>(X, Wq, bq, (void*)qb, row0, tid, wlds, xs, myb);
  else if (m == 1) proj32<1>(X, Wk, bk, (void*)kb, row0, tid, wlds, xs, myb);
  else             proj32<2>(X, Wv, bv, (void*)vb, row0, tid, wlds, xs, myb);
}

__global__ __launch_bounds__(256)
void oproj_kernel(const float* __restrict__ A, const float* __restrict__ Wo,
                  const float* __restrict__ bo, float* __restrict__ out)
{
  __shared__ __align__(16) unsigned short wlds[16384];   // 32 KB
  __shared__ __align__(16) unsigned short xs[4096];      // 8 KB
  proj32<3>(A, Wo, bo, (void*)out, blockIdx.x * 32, threadIdx.x, wlds, xs, nullptr);
}

// ---------------------------------------------------------------------------
// 32q x 32k macro-step compute (operands preloaded by the caller's pipeline).
// QK^T: S^T = mfma_32x32x16_bf16(A=K-rows, B=Q) -> C[key][q]:
//   col q = l&31, row key = (reg&3)+8*(reg>>2)+4*(l>>5)   [guide m74/m101]
// Sigmoid per element; pack pairs to bf16; 4 permlane32_swaps convert the
// C layout to the PV A-operand layout (P[q=l&31][key=(l>>5)*8+j]).
// PV: two mfma_32x32x16 (keys 0-15, 16-31). V B-frag col n=8 forced to 1.0
// -> acc col 8 = denominator (cols 9-31 junk).
// ---------------------------------------------------------------------------
template<bool DIAG>
__device__ __forceinline__
float16v compute32(U16x8 kf, uint4 va, uint4 vb, U16x8 qf, float16v acc,
                   int lane, bool is8)
{
  U16x8 v1, v2;
  {
    const uint4 ones = make_uint4(0x3F803F80u, 0x3F803F80u,
                                  0x3F803F80u, 0x3F803F80u);
    v1.u = is8 ? ones : va;
    v2.u = is8 ? ones : vb;
  }

  float16v st = MFMA32(kf.s, qf.s, zero16());

  unsigned u[8];
  #pragma unroll
  for (int i = 0; i < 8; ++i) {
    float s0 = RCPF(1.f + EXP2F(st[2 * i]));      // Q carries -scale*log2e
    float s1 = RCPF(1.f + EXP2F(st[2 * i + 1]));
    if (DIAG) {                                   // exact: sigma(-1e9)==0
      const int rb = ((2 * i) & 3) + 8 * (i >> 1) + ((lane >> 5) << 2);
      const int q_ = lane & 31;
      s0 = (rb     <= q_) ? s0 : 0.f;
      s1 = (rb + 1 <= q_) ? s1 : 0.f;
    }
    const unsigned b0 = __float_as_uint(s0) + 0x8000u;  // round-half-up bf16
    const unsigned b1 = __float_as_uint(s1) + 0x8000u;
    u[i] = __builtin_amdgcn_perm(b1, b0, 0x07060302u);
  }

  lane32swap(u[0], u[2]);
  lane32swap(u[1], u[3]);
  lane32swap(u[4], u[6]);
  lane32swap(u[5], u[7]);

  U16x8 pa, pb;
  pa.u = make_uint4(u[0], u[1], u[2], u[3]);
  pb.u = make_uint4(u[4], u[5], u[6], u[7]);
  acc = MFMA32(pa.s, v1.s, acc);                  // keys 0-15
  acc = MFMA32(pb.s, v2.s, acc);                  // keys 16-31
  return acc;
}

// run k-tiles [a,b) of tile T with prefetch-1-deep K/V pipeline;
// b == T+1 means this wave owns T's diag step (it is the last).
__device__ __forceinline__
void seg32(const uint4* __restrict__ Kg, const unsigned short* __restrict__ Vtbh,
           U16x8 qf, int T, int a, int b, float16v &acc,
           int lane, unsigned voff, bool is8)
{
  if (a >= b) return;
  const int l31 = lane & 31;
  const bool hasDiag = (b == T + 1);
  const int last = b - 1;

  U16x8 kf; kf.u = Kg[32 * a + l31];
  uint4 va = *(const uint4*)(Vtbh + 256 * a + voff);
  uint4 vb = *(const uint4*)(Vtbh + 256 * a + 128 + voff);

  for (int t = a; t < last; ++t) {
    U16x8 kn; kn.u = Kg[32 * (t + 1) + l31];      // t+1 <= last <= 63
    const uint4 vna = *(const uint4*)(Vtbh + 256 * (t + 1) + voff);
    const uint4 vnb = *(const uint4*)(Vtbh + 256 * (t + 1) + 128 + voff);
    acc = compute32<false>(kf, va, vb, qf, acc, lane, is8);
    kf = kn; va = vna; vb = vnb;
  }
  if (hasDiag) acc = compute32<true >(kf, va, vb, qf, acc, lane, is8);
  else         acc = compute32<false>(kf, va, vb, qf, acc, lane, is8);
}

// epilogue: den = acc col 8 (same half, lane (l&32)|8); store d = l&31 < 8
__device__ __forceinline__
void epilogue32(float16v acc, int T, int bh, int lane, float* __restrict__ out)
{
  const int b_ = bh >> 4, h = bh & 15;
  const int n = lane & 31;
  const int pidx = ((lane & 32) | 8) << 2;
  const int rowb = 32 * T + ((lane >> 5) << 2);
  #pragma unroll
  for (int reg = 0; reg < 16; ++reg) {
    const float den = __int_as_float(
        __builtin_amdgcn_ds_bpermute(pidx, __float_as_int(acc[reg])));
    const float val = acc[reg] * RCPF(den);       // den > 0
    const int row = rowb + (reg & 3) + 8 * (reg >> 2);
    if (n < 8)
      out[(size_t)(b_ * SEQ + row) * EDIM + h * HDIM + n] = val;
  }
}

// combine helpers: [64][17] float rows (stride 17 = odd -> 2-way-free banks)
__device__ __forceinline__
void cmb_store(float* slot, int lane, float16v v) {
  #pragma unroll
  for (int i = 0; i < 16; ++i) slot[lane * 17 + i] = v[i];
}
__device__ __forceinline__
void cmb_add(float* slot, int lane, float16v &v) {
  #pragma unroll
  for (int i = 0; i < 16; ++i) v[i] += slot[lane * 17 + i];
}

// ---------------------------------------------------------------------------
// Causal sigmoid-attention v15: 32x32 macro-steps + prefetch pipeline +
// 4-wave split. Fold-pair (L=g, H=63-g) = 65 macro-steps flattened and
// chunked {0,17,33,49,65} over 4 waves. Tree combine: w1->w0, w3->w2,
// w2->w0. Grid 2048 x 256thr = 8 blocks/CU (LDS 17KB), ~20+ waves/CU.
// blockIdx low 6 bits = bh -> XCD = bh%8 (L2 locality).
// ---------------------------------------------------------------------------
__global__ __launch_bounds__(256, 4)
void attn_kernel(const unsigned* __restrict__ Qb, const unsigned* __restrict__ Kb,
                 const unsigned* __restrict__ Vb, float* __restrict__ out)
{
  __shared__ float cmb[2][2][64 * 17];            // [slot][L/H] = 17408 B

  const int bh   = blockIdx.x & 63;
  const int g    = blockIdx.x >> 6;               // 0..31
  const int w    = threadIdx.x >> 6;              // 0..3
  const int lane = threadIdx.x & 63;
  const int L = g, H = 63 - g;

  const uint4* Kg = (const uint4*)Kb + (size_t)bh * 2048;
  const uint4* Qg = (const uint4*)Qb + (size_t)bh * 2048;
  const unsigned short* Vtbh = (const unsigned short*)Vb + (size_t)bh * SEQ * HDIM;

  const unsigned voff = (unsigned)((lane & 7) * 16 + ((lane >> 5) << 3));
  const bool is8 = (lane & 31) == 8;

  // Q B-frags: lanes<32 hold Q-row (dims 0-7) for q = lane; half1 zero
  U16x8 qfl, qfh;
  {
    const uint4 zz = make_uint4(0u, 0u, 0u, 0u);
    qfl.u = (lane < 32) ? Qg[32 * L + lane] : zz;
    qfh.u = (lane < 32) ? Qg[32 * H + lane] : zz;
  }

  float16v accL = zero16();
  float16v accH = zero16();

  // flattened 65-step chunks: {0,17,33,49,65}
  const int st_ = (w == 0) ? 0 : (w == 1) ? 17 : (w == 2) ? 33 : 49;
  const int en_ = (w == 0) ? 17 : (w == 1) ? 33 : (w == 2) ? 49 : 65;
  const int Lp1 = L + 1;
  const int aL = (st_ < Lp1) ? st_ : Lp1;
  const int bL = (en_ < Lp1) ? en_ : Lp1;
  int aH = st_ - Lp1; if (aH < 0) aH = 0;
  int bH = en_ - Lp1; if (bH > H + 1) bH = H + 1;

  seg32(Kg, Vtbh, qfl, L, aL, bL, accL, lane, voff, is8);
  seg32(Kg, Vtbh, qfh, H, aH, bH, accH, lane, voff, is8);

  // tree combine: (w0 += w1) and (w2 += w3), then w0 += w2
  if (w == 1) { cmb_store(cmb[0][0], lane, accL); cmb_store(cmb[0][1], lane, accH); }
  if (w == 3) { cmb_store(cmb[1][0], lane, accL); cmb_store(cmb[1][1], lane, accH); }
  __syncthreads();
  if (w == 0) { cmb_add(cmb[0][0], lane, accL); cmb_add(cmb[0][1], lane, accH); }
  if (w == 2) { cmb_add(cmb[1][0], lane, accL); cmb_add(cmb[1][1], lane, accH); }
  __syncthreads();
  if (w == 2) { cmb_store(cmb[0][0], lane, accL); cmb_store(cmb[0][1], lane, accH); }
  __syncthreads();
  if (w == 0) {
    cmb_add(cmb[0][0], lane, accL);
    cmb_add(cmb[0][1], lane, accH);
    epilogue32(accL, L, bh, lane, out);
    epilogue32(accH, H, bh, lane, out);
  }
}

// ---------------------------------------------------------------------------
extern "C" void kernel_launch(void* const* d_in, const int* in_sizes, int n_in,
                              void* d_out, int out_size, void* d_ws, size_t ws_size,
                              hipStream_t stream)
{
  const float* x  = (const float*)d_in[0];
  const float* Wq = (const float*)d_in[1];
  const float* bq = (const float*)d_in[2];
  const float* Wk = (const float*)d_in[3];
  const float* bk = (const float*)d_in[4];
  const float* Wv = (const float*)d_in[5];
  const float* bv = (const float*)d_in[6];
  const float* Wo = (const float*)d_in[7];
  const float* bo = (const float*)d_in[8];

  float* ws = (float*)d_ws;
  // layout: (64K floats reserved) | attn 1048576 f | Qb, Kb, Vt 524288 dw each
  float*    attn = ws + 65536;
  unsigned* Qb   = (unsigned*)(ws + 65536 + 1048576);
  unsigned* Kb   = Qb + (size_t)524288;
  unsigned* Vb   = Kb + (size_t)524288;

  qkv_kernel<<<dim3(NROW / 32, 3), 256, 0, stream>>>(x, Wq, Wk, Wv, bq, bk, bv,
                                                     Qb, Kb, Vb);
  attn_kernel<<<dim3(2048), 256, 0, stream>>>(Qb, Kb, Vb, attn);
  oproj_kernel<<<dim3(NROW / 32), 256, 0, stream>>>(attn, Wo, bo, (float*)d_out);
}

// Round 15
// 122.166 us; speedup vs baseline: 1.0182x; 1.0127x over previous
//
#include <hip/hip_runtime.h>
#include <math.h>

#define EDIM 128
#define NHEAD 16
#define HDIM 8
#define SEQ 2048
#define BATCH 4
#define NROW (BATCH*SEQ)            // 8192
// -scale*log2(e): folded into Q at projection time so sigmoid = rcp(1+exp2(dot))
#define QNEG (-0.35355339059327373f * 1.4426950408889634f)

#if __has_builtin(__builtin_amdgcn_exp2f)
#define EXP2F(x) __builtin_amdgcn_exp2f(x)
#else
#define EXP2F(x) exp2f(x)
#endif
#define RCPF(x) __builtin_amdgcn_rcpf(x)

typedef __attribute__((ext_vector_type(8))) short short8v;
typedef __attribute__((ext_vector_type(4))) short short4v;
typedef __attribute__((ext_vector_type(4))) float float4v;

union U16x8 { uint4 u; short8v s; };
union U16x4 { uint2 u; short4v s; };

#if __has_builtin(__builtin_amdgcn_mfma_f32_16x16x16bf16_1k)
#define MFMA_PV(a,b,c) __builtin_amdgcn_mfma_f32_16x16x16bf16_1k(a,b,c,0,0,0)
#else
static __device__ __forceinline__ float4v mfma_pv_asm(short4v a, short4v b, float4v c) {
  float4v d;
  asm("v_mfma_f32_16x16x16_bf16 %0, %1, %2, %3" : "=v"(d) : "v"(a), "v"(b), "v"(c));
  return d;
}
#define MFMA_PV(a,b,c) mfma_pv_asm(a,b,c)
#endif

// pack two floats to bf16x2, round-to-nearest-even-ish (values finite)
__device__ __forceinline__ unsigned pk_bf16(float a, float b) {
  unsigned ua = __float_as_uint(a), ub = __float_as_uint(b);
  unsigned lo = (ua + 0x7fffu + ((ua >> 16) & 1u)) >> 16;
  unsigned hi = (ub + 0x7fffu + ((ub >> 16) & 1u)) & 0xffff0000u;
  return lo | hi;
}

// A-frags from swizzled LDS: A lane l: A[m=l&15][k=(l>>4)*8+j]
__device__ __forceinline__
void afrags(const unsigned short* xs, int lq, int qd, short8v a[4])
{
  #pragma unroll
  for (int kk = 0; kk < 4; ++kk) {
    const unsigned addr =
        (unsigned)(lq * 256 + kk * 64 + qd * 16) ^ (unsigned)((lq & 7) << 4);
    a[kk] = *(const short8v*)((const char*)xs + addr);
  }
}

// ---------------------------------------------------------------------------
// 32-row x 128-col MFMA projection block, W staged per-block into LDS.
// (unchanged from R12 — byte-identical outputs)
// ---------------------------------------------------------------------------
template<int MODE>
__device__ __forceinline__
void proj32(const float* __restrict__ X, const float* __restrict__ W,
            const float* __restrict__ bias, void* __restrict__ out,
            int row0, int tid,
            unsigned short* wlds, unsigned short* xs, unsigned short* bnc)
{
  // ---- stage W: 2 threads per row, 64 cols (16 float4) each, coalesced ----
  {
    const int n = tid >> 1, h = (tid & 1) * 64;
    const float4* src = (const float4*)(W + (size_t)n * EDIM + h);
    const unsigned xr = (unsigned)((n & 7) << 4);
    #pragma unroll
    for (int j = 0; j < 8; ++j) {
      const float4 f0 = src[2 * j], f1 = src[2 * j + 1];
      const uint4 v = make_uint4(pk_bf16(f0.x, f0.y), pk_bf16(f0.z, f0.w),
                                 pk_bf16(f1.x, f1.y), pk_bf16(f1.z, f1.w));
      *(uint4*)((char*)wlds + ((unsigned)(n * 256 + h * 2 + j * 16) ^ xr)) = v;
    }
  }
  // ---- stage X: 8 threads per row (32 rows), 16 cols each ----
  {
    const int r = tid >> 3, c = tid & 7;
    const float4* src = (const float4*)(X + (size_t)(row0 + r) * EDIM + c * 16);
    const unsigned xr = (unsigned)((r & 7) << 4);
    const float4 f0 = src[0], f1 = src[1], f2 = src[2], f3 = src[3];
    const uint4 v0 = make_uint4(pk_bf16(f0.x, f0.y), pk_bf16(f0.z, f0.w),
                                pk_bf16(f1.x, f1.y), pk_bf16(f1.z, f1.w));
    const uint4 v1 = make_uint4(pk_bf16(f2.x, f2.y), pk_bf16(f2.z, f2.w),
                                pk_bf16(f3.x, f3.y), pk_bf16(f3.z, f3.w));
    *(uint4*)((char*)xs + ((unsigned)(r * 256 + c * 32) ^ xr)) = v0;
    *(uint4*)((char*)xs + ((unsigned)(r * 256 + c * 32 + 16) ^ xr)) = v1;
  }
  __syncthreads();

  const int lane = tid & 63, wv = tid >> 6;
  const int lq = lane & 15, qd = lane >> 4;
  const int n0 = wv * 32;

  // ---- B-frags once per wave (two 16-col tiles) ----
  short8v b0[4], b1[4];
  #pragma unroll
  for (int kk = 0; kk < 4; ++kk) {
    const unsigned ad = (unsigned)((n0 + lq) * 256 + kk * 64 + qd * 16)
                      ^ (unsigned)((lq & 7) << 4);
    b0[kk] = *(const short8v*)((const char*)wlds + ad);
    b1[kk] = *(const short8v*)((const char*)wlds + ad + 4096);  // +16 rows
  }

  const int nA = n0 + lq, nB = nA + 16;
  const float bzA = bias[nA], bzB = bias[nB];
  const int b_ = row0 >> 11;

  #pragma unroll
  for (int rt = 0; rt < 2; ++rt) {
    const int rowt = row0 + rt * 16;
    short8v a[4];
    afrags(xs + rt * 2048, lq, qd, a);

    float4v D0 = {0.f, 0.f, 0.f, 0.f}, D1 = {0.f, 0.f, 0.f, 0.f};
    #pragma unroll
    for (int kk = 0; kk < 4; ++kk) {
      D0 = __builtin_amdgcn_mfma_f32_16x16x32_bf16(a[kk], b0[kk], D0, 0, 0, 0);
      D1 = __builtin_amdgcn_mfma_f32_16x16x32_bf16(a[kk], b1[kk], D1, 0, 0, 0);
    }

    if (MODE == 3) {
      float* of = (float*)out + (size_t)(rowt + qd * 4) * EDIM + nA;
      #pragma unroll
      for (int r = 0; r < 4; ++r) {
        of[r * EDIM]      = D0[r] + bzA;
        of[r * EDIM + 16] = D1[r] + bzB;
      }
      continue;
    }

    const int srel = rowt & (SEQ - 1);

    if (MODE == 2) {
      // Vt[bh][tg][d][si]: row-tile = one 16-s tile; si = qd*4 + r.
      const int tg = srel >> 4;
      unsigned short* oU = (unsigned short*)out;
      {
        const int bh = b_ * NHEAD + (nA >> 3), dv = nA & 7;
        uint2 p;
        p.x = pk_bf16(D0[0] + bzA, D0[1] + bzA);
        p.y = pk_bf16(D0[2] + bzA, D0[3] + bzA);
        *(uint2*)(oU + (size_t)bh * (SEQ * HDIM) + tg * 128 + dv * 16 + qd * 4) = p;
      }
      {
        const int bh = b_ * NHEAD + (nB >> 3), dv = nB & 7;
        uint2 p;
        p.x = pk_bf16(D1[0] + bzB, D1[1] + bzB);
        p.y = pk_bf16(D1[2] + bzB, D1[3] + bzB);
        *(uint2*)(oU + (size_t)bh * (SEQ * HDIM) + tg * 128 + dv * 16 + qd * 4) = p;
      }
      continue;
    }

    // MODE 0/1: bounce both 16x16 tiles through padded LDS ([16][20] u16),
    // then contiguous 256B uint4 stores (one [bh][s][8] row per lane).
    #pragma unroll
    for (int r = 0; r < 4; ++r) {
      float vA = D0[r] + bzA, vB = D1[r] + bzB;
      if (MODE == 0) { vA *= QNEG; vB *= QNEG; }
      const int m = qd * 4 + r;
      bnc[m * 20 + lq]       = (unsigned short)pk_bf16(vA, 0.f);
      bnc[320 + m * 20 + lq] = (unsigned short)pk_bf16(vB, 0.f);
    }
    __syncthreads();                              // LDS write->read order

    const int mm   = lane & 15;
    const int half = (lane >> 4) & 1;
    const int tile = lane >> 5;
    const unsigned short* sp = bnc + tile * 320 + mm * 20 + half * 8;
    const uint2 w0 = *(const uint2*)sp;
    const uint2 w1 = *(const uint2*)(sp + 4);
    const int bh = b_ * NHEAD + wv * 4 + tile * 2 + half;
    unsigned short* dp = (unsigned short*)out + ((size_t)bh * SEQ + srel + mm) * 8;
    *(uint4*)dp = make_uint4(w0.x, w0.y, w1.x, w1.y);
    __syncthreads();                              // bnc reuse guard (next rt)
  }
}

__global__ __launch_bounds__(256)
void qkv_kernel(const float* __restrict__ X,
                const float* __restrict__ Wq, const float* __restrict__ Wk,
                const float* __restrict__ Wv,
                const float* __restrict__ bq, const float* __restrict__ bk,
                const float* __restrict__ bv,
                unsigned* __restrict__ qb, unsigned* __restrict__ kb,
                unsigned* __restrict__ vb, unsigned short* __restrict__ onesb)
{
  __shared__ __align__(16) unsigned short wlds[16384];   // 32 KB
  __shared__ __align__(16) unsigned short xs[4096];      // 8 KB
  __shared__ __align__(16) unsigned short bnc[4 * 640];  // 5 KB
  const int tid = threadIdx.x;
  const int row0 = blockIdx.x * 32;
  unsigned short* myb = bnc + (tid >> 6) * 640;
  const int m = blockIdx.y;
  // fill the attn denominator ones-tile (bf16 1.0 x 128); attn launches after
  if (m == 0 && blockIdx.x == 0 && tid < 32)
    ((uint2*)onesb)[tid] = make_uint2(0x3F803F80u, 0x3F803F80u);
  if (m == 0)      proj32<0>(X, Wq, bq, (void*)qb, row0, tid, wlds, xs, myb);
  else if (m == 1) proj32<1>(X, Wk, bk, (void*)kb, row0, tid, wlds, xs, myb);
  else             proj32<2>(X, Wv, bv, (void*)vb, row0, tid, wlds, xs, myb);
}

__global__ __launch_bounds__(256)
void oproj_kernel(const float* __restrict__ A, const float* __restrict__ Wo,
                  const float* __restrict__ bo, float* __restrict__ out)
{
  __shared__ __align__(16) unsigned short wlds[16384];   // 32 KB
  __shared__ __align__(16) unsigned short xs[4096];      // 8 KB
  proj32<3>(A, Wo, bo, (void*)out, blockIdx.x * 32, threadIdx.x, wlds, xs, nullptr);
}

// ---------------------------------------------------------------------------
// One 16q x 16k MFMA step (verified 4-rcp form; attn is issue-saturated so
// every instruction counts — batched-rcp and cvt_pk variants both measured
// slower/wrong; keep this).
// S^T = mfma_16x16x32_bf16(A=K-rows, B=Q-frag) -> C[key][q]. Sigmoid
// elementwise; C-register reinterpreted as A-operand of mfma_16x16x16 gives
// the UN-transposed P, so out[q][d] = mfma(A=P, B=V-frag, acc). V-frag col 8
// comes from a ones-tile via per-lane base pointer (no per-step cndmask).
// ---------------------------------------------------------------------------
template<bool DIAG>
__device__ __forceinline__
float4v attn_step(short8v kf, short8v qf, short4v vf, float4v acc,
                  int laneq, int quad)
{
  const float4v z = {0.f, 0.f, 0.f, 0.f};
  float4v st = __builtin_amdgcn_mfma_f32_16x16x32_bf16(kf, qf, z, 0, 0, 0);
  unsigned rb[4];
  #pragma unroll
  for (int r = 0; r < 4; ++r) {
    float s = RCPF(1.f + EXP2F(st[r]));           // Q carries -scale*log2e
    if (DIAG) s = (4 * quad + r <= laneq) ? s : 0.f;  // exact: sigma(-1e9)==0
    rb[r] = __float_as_uint(s) + 0x8000u;         // round-half-up to bf16
  }
  U16x4 p;
  p.u.x = __builtin_amdgcn_perm(rb[1], rb[0], 0x07060302u);
  p.u.y = __builtin_amdgcn_perm(rb[3], rb[2], 0x07060302u);
  return MFMA_PV(p.s, vf, acc);                   // A = P[q][k], B = V[k][d]
}

// epilogue: den = acc col 8; normalize and store rows of tile T
__device__ __forceinline__
void epilogue(float4v acc, int T, int bh, int laneq, int quad,
              float* __restrict__ out)
{
  const int b_ = bh >> 4, h = bh & 15;
  const int pidx = (quad * 16 + 8) << 2;          // lane holding col 8
  #pragma unroll
  for (int r = 0; r < 4; ++r) {
    const float den = __int_as_float(
        __builtin_amdgcn_ds_bpermute(pidx, __float_as_int(acc[r])));
    const float val = acc[r] * RCPF(den);         // den > 0
    const int row = 16 * T + 4 * quad + r;
    if (laneq < 8)
      out[(size_t)(b_ * SEQ + row) * EDIM + h * HDIM + laneq] = val;
  }
}

// ---------------------------------------------------------------------------
// Causal sigmoid-attention v16: v13 schedule (split w0 loops) + ones-tile
// V-frag base pointers (denominator lanes: vbase=ones, vstride=0 — removes
// 2 cndmask + address math per step from the saturated issue stream).
// blockIdx low 6 bits = bh -> XCD = bh%8 (L2 locality).
// ---------------------------------------------------------------------------
__global__ __launch_bounds__(128, 8)
void attn_kernel(const unsigned* __restrict__ Qb, const unsigned* __restrict__ Kb,
                 const unsigned* __restrict__ Vb, float* __restrict__ out,
                 const unsigned short* __restrict__ onesb)
{
  __shared__ float cmb[2][64][4];                 // 2 KB

  const int bh    = blockIdx.x & 63;
  const int g     = blockIdx.x >> 6;              // 0..63
  const int w     = threadIdx.x >> 6;
  const int lane  = threadIdx.x & 63;
  const int laneq = lane & 15;
  const int quad  = lane >> 4;
  const int L = g, H = 127 - g;
  const int mL = (L + 1) >> 1, mH = (H + 1) >> 1;
  const int d   = laneq & 7;
  const bool is8 = (laneq == 8);

  const uint4* Kg = (const uint4*)Kb + (size_t)bh * 2048;
  const uint4* Qg = (const uint4*)Qb + (size_t)bh * 2048;
  const unsigned short* Vtbh = (const unsigned short*)Vb + (size_t)bh * SEQ * HDIM;

  // per-lane V-frag base/stride: denominator lanes walk a static ones-tile
  const unsigned short* vbase = is8 ? onesb + 4 * quad
                                    : Vtbh + d * 16 + 4 * quad;
  const int vstep = is8 ? 0 : 128;                // u16 per k-tile

  // Q B-frags: lanes<16 hold the 8-dim row in quad 0 (k=0..7); zero others
  U16x8 qfl, qfh;
  {
    const uint4 rl = Qg[16 * L + laneq];
    const uint4 rh = Qg[16 * H + laneq];
    qfl.u = (lane < 16) ? rl : make_uint4(0u, 0u, 0u, 0u);
    qfh.u = (lane < 16) ? rh : make_uint4(0u, 0u, 0u, 0u);
  }

  float4v accL = {0.f, 0.f, 0.f, 0.f};
  float4v accH = {0.f, 0.f, 0.f, 0.f};

  if (w == 0) {
    // dual loop [0,mL): L+H share k/v frags; then H-only [mL,mH). No diags.
    U16x8 kf; kf.u = Kg[laneq];
    const unsigned short* vq = vbase;
    U16x4 vf; vf.u = *(const uint2*)vq;
    int t = 0;
    #pragma unroll 2
    for (; t < mL; ++t) {
      U16x8 kn; kn.u = Kg[16 * (t + 1) + laneq];  // t+1 <= mL <= 32: in-bounds
      const unsigned short* vp = vq + vstep;
      U16x4 vn; vn.u = *(const uint2*)vp;
      accL = attn_step<false>(kf.s, qfl.s, vf.s, accL, laneq, quad);
      accH = attn_step<false>(kf.s, qfh.s, vf.s, accH, laneq, quad);
      kf = kn; vf = vn; vq = vp;
    }
    #pragma unroll 2
    for (; t < mH; ++t) {
      U16x8 kn; kn.u = Kg[16 * (t + 1) + laneq];  // t+1 <= mH <= 64: in-bounds
      const unsigned short* vp = vq + vstep;
      U16x4 vn; vn.u = *(const uint2*)vp;
      accH = attn_step<false>(kf.s, qfh.s, vf.s, accH, laneq, quad);
      kf = kn; vf = vn; vq = vp;
    }
  } else {
    // L segment: [mL, L], diag at L
    U16x8 kf; kf.u = Kg[16 * mL + laneq];
    const unsigned short* vq = vbase + (size_t)vstep * mL;
    U16x4 vf; vf.u = *(const uint2*)vq;
    #pragma unroll 2
    for (int t = mL; t < L; ++t) {
      U16x8 kn; kn.u = Kg[16 * (t + 1) + laneq];
      const unsigned short* vp = vq + vstep;
      U16x4 vn; vn.u = *(const uint2*)vp;
      accL = attn_step<false>(kf.s, qfl.s, vf.s, accL, laneq, quad);
      kf = kn; vf = vn; vq = vp;
    }
    accL = attn_step<true>(kf.s, qfl.s, vf.s, accL, laneq, quad);
    // H segment: [mH, H], diag at H
    kf.u = Kg[16 * mH + laneq];
    vq = vbase + (size_t)vstep * mH;
    vf.u = *(const uint2*)vq;
    #pragma unroll 2
    for (int t = mH; t < H; ++t) {
      U16x8 kn; kn.u = Kg[16 * (t + 1) + laneq];  // t+1 <= H = 127: in-bounds
      const unsigned short* vp = vq + vstep;
      U16x4 vn; vn.u = *(const uint2*)vp;
      accH = attn_step<false>(kf.s, qfh.s, vf.s, accH, laneq, quad);
      kf = kn; vf = vn; vq = vp;
    }
    accH = attn_step<true>(kf.s, qfh.s, vf.s, accH, laneq, quad);

    *(float4*)&cmb[0][lane][0] = make_float4(accL[0], accL[1], accL[2], accL[3]);
    *(float4*)&cmb[1][lane][0] = make_float4(accH[0], accH[1], accH[2], accH[3]);
  }
  __syncthreads();

  if (w == 0) {
    const float4 pL = *(const float4*)&cmb[0][lane][0];
    const float4 pH = *(const float4*)&cmb[1][lane][0];
    accL[0] += pL.x; accL[1] += pL.y; accL[2] += pL.z; accL[3] += pL.w;
    accH[0] += pH.x; accH[1] += pH.y; accH[2] += pH.z; accH[3] += pH.w;
    epilogue(accL, L, bh, laneq, quad, out);
    epilogue(accH, H, bh, laneq, quad, out);
  }
}

// ---------------------------------------------------------------------------
extern "C" void kernel_launch(void* const* d_in, const int* in_sizes, int n_in,
                              void* d_out, int out_size, void* d_ws, size_t ws_size,
                              hipStream_t stream)
{
  const float* x  = (const float*)d_in[0];
  const float* Wq = (const float*)d_in[1];
  const float* bq = (const float*)d_in[2];
  const float* Wk = (const float*)d_in[3];
  const float* bk = (const float*)d_in[4];
  const float* Wv = (const float*)d_in[5];
  const float* bv = (const float*)d_in[6];
  const float* Wo = (const float*)d_in[7];
  const float* bo = (const float*)d_in[8];

  float* ws = (float*)d_ws;
  // layout: ones 128 f (in reserved 64K-float region) | attn 1048576 f |
  //         Qb, Kb, Vt 524288 dwords each
  unsigned short* onesb = (unsigned short*)ws;
  float*    attn = ws + 65536;
  unsigned* Qb   = (unsigned*)(ws + 65536 + 1048576);
  unsigned* Kb   = Qb + (size_t)524288;
  unsigned* Vb   = Kb + (size_t)524288;

  qkv_kernel<<<dim3(NROW / 32, 3), 256, 0, stream>>>(x, Wq, Wk, Wv, bq, bk, bv,
                                                     Qb, Kb, Vb, onesb);
  attn_kernel<<<dim3(4096), 128, 0, stream>>>(Qb, Kb, Vb, attn, onesb);
  oproj_kernel<<<dim3(NROW / 32), 256, 0, stream>>>(attn, Wo, bo, (float*)d_out);
}